// Round 16
// baseline (111.379 us; speedup 1.0000x reference)
//
#include <hip/hip_runtime.h>
#include <hip/hip_bf16.h>

#define IN_DIM 2048
#define OUT_DIM 2048
#define NE 8
#define M_TOT 8192          // B*S = 4*2048
#define NB 4                // batches
#define RK 96               // 8 shared + 64 expert + 24 zero pad (K of delta GEMM)

typedef short short8 __attribute__((ext_vector_type(8)));
typedef float floatx4 __attribute__((ext_vector_type(4)));
typedef unsigned short us;

__device__ __forceinline__ us f2bf(float f) {
    __hip_bfloat16 h = __float2bfloat16(f);   // native RNE cast
    return *reinterpret_cast<us*>(&h);
}

__device__ __forceinline__ short8 cvt8(float4 v0, float4 v1) {
    short8 o;
    o[0] = (short)f2bf(v0.x); o[1] = (short)f2bf(v0.y);
    o[2] = (short)f2bf(v0.z); o[3] = (short)f2bf(v0.w);
    o[4] = (short)f2bf(v1.x); o[5] = (short)f2bf(v1.y);
    o[6] = (short)f2bf(v1.z); o[7] = (short)f2bf(v1.w);
    return o;
}

__device__ __forceinline__ void gld_lds16(const void* g, void* l) {
    __builtin_amdgcn_global_load_lds(
        (const __attribute__((address_space(1))) void*)g,
        (__attribute__((address_space(3))) void*)l, 16, 0, 0);
}

// ===========================================================================
// Main GEMM — FROZEN proven kernel (R4 schedule + XCD-chunked mapping:
// 67.1us, FETCH 49MB, 0 conflicts). Do not touch.
// ===========================================================================

template <int KX>
__device__ __forceinline__ void stage2(const us* src, char* lds) {
    gld_lds16(src, lds);
    gld_lds16(src + 128 * KX, lds + 8192);
}

__device__ __forceinline__ void mfma_quad(floatx4 (&acc)[8][4], const short8 (&af)[4],
                                          const short8 (&bf)[4], int mq) {
#pragma unroll
    for (int i = 0; i < 4; ++i)
#pragma unroll
        for (int ni = 0; ni < 4; ++ni)
            acc[mq * 4 + i][ni] =
                __builtin_amdgcn_mfma_f32_16x16x32_bf16(af[i], bf[ni], acc[mq * 4 + i][ni], 0, 0, 0);
}

template <int KX, int SM, int VM0, int VM2, bool RD3>
__device__ __forceinline__ void ktile(
    const us* __restrict__ pA, const us* __restrict__ pB, int k1, int k2,
    const char* smC, const char* smN, char* lwC, char* lwN,
    int ab, int bb,
    short8 (&afA)[4], short8 (&afB)[4], short8 (&bfA)[4], short8 (&bfB)[4],
    floatx4 (&acc)[8][4])
{
    // ---------- p0 ----------
#pragma unroll
    for (int i = 0; i < 4; ++i) afB[i] = *(const short8*)(smC + ab + (4 + i) * 1024);
    asm volatile("s_waitcnt lgkmcnt(4)" ::: "memory");
    __builtin_amdgcn_sched_barrier(0);
    __builtin_amdgcn_s_setprio(1);
    mfma_quad(acc, afA, bfA, 0);
    __builtin_amdgcn_s_setprio(0);
    if (SM & 1) stage2<KX>(pA + k1 + 32, lwN + 32768);
    if (VM0 == 8)      asm volatile("s_waitcnt vmcnt(8)" ::: "memory");
    else if (VM0 == 0) asm volatile("s_waitcnt vmcnt(0)" ::: "memory");
    __builtin_amdgcn_s_barrier();

    // ---------- p1 ----------
#pragma unroll
    for (int i = 0; i < 4; ++i) afA[i] = *(const short8*)(smC + 32768 + ab + (4 + i) * 1024);
#pragma unroll
    for (int i = 0; i < 4; ++i) bfB[i] = *(const short8*)(smC + 32768 + bb + i * 1024);
    asm volatile("s_waitcnt lgkmcnt(8)" ::: "memory");
    __builtin_amdgcn_sched_barrier(0);
    __builtin_amdgcn_s_setprio(1);
    mfma_quad(acc, afB, bfA, 1);
    __builtin_amdgcn_s_setprio(0);
    if (SM & 2) stage2<KX>(pB + k2, lwC + 16384);
    __builtin_amdgcn_s_barrier();

    // ---------- p2 ----------
#pragma unroll
    for (int i = 0; i < 4; ++i) afB[i] = *(const short8*)(smC + 32768 + ab + i * 1024);
    asm volatile("s_waitcnt lgkmcnt(4)" ::: "memory");
    __builtin_amdgcn_sched_barrier(0);
    __builtin_amdgcn_s_setprio(1);
    mfma_quad(acc, afA, bfB, 1);
    __builtin_amdgcn_s_setprio(0);
    if (SM & 4) stage2<KX>(pA + k2, lwC);
    if (VM2 == 8)      asm volatile("s_waitcnt vmcnt(8)" ::: "memory");
    else if (VM2 == 4) asm volatile("s_waitcnt vmcnt(4)" ::: "memory");
    __builtin_amdgcn_s_barrier();

    // ---------- p3 ----------
    if (RD3) {
#pragma unroll
        for (int i = 0; i < 4; ++i) afA[i] = *(const short8*)(smN + ab + i * 1024);
#pragma unroll
        for (int i = 0; i < 4; ++i) bfA[i] = *(const short8*)(smN + bb + i * 1024);
        asm volatile("s_waitcnt lgkmcnt(8)" ::: "memory");
    } else {
        asm volatile("s_waitcnt lgkmcnt(0)" ::: "memory");
    }
    __builtin_amdgcn_sched_barrier(0);
    __builtin_amdgcn_s_setprio(1);
    mfma_quad(acc, afB, bfB, 0);
    __builtin_amdgcn_s_setprio(0);
    if (SM & 8) stage2<KX>(pB + k2 + 32, lwC + 49152);
    __builtin_amdgcn_s_barrier();
}

template <int KX, bool PB>
__global__ __launch_bounds__(512) void main_gemm_t(const us* __restrict__ A,
                                                   const us* __restrict__ Bw,
                                                   const float* __restrict__ bias,
                                                   float* __restrict__ out) {
    extern __shared__ char smem[];
    constexpr int NT = KX / 64;            // 32 or 34 K-tiles
    int tid = threadIdx.x;
    int lane = tid & 63, w = tid >> 6;
    int wm = w >> 2, wn = w & 3;           // 2M x 4N waves; per-wave C = 128x64
    int rlo = lane & 15, kq = lane >> 4;

    // XCD-chunked swizzle (proven): 256 blocks = 8 XCDs x 32 contiguous
    int b = blockIdx.x;
    int bs = (b & 7) * 32 + (b >> 3);
    int m0 = (bs >> 3) * 256, n0 = (bs & 7) * 256;

    const us* B = PB ? (Bw + (size_t)(m0 >> 11) * OUT_DIM * KX) : Bw;

    int swz = (kq ^ ((rlo >> 1) & 3)) * 16;
    int ab = (wm * 128 + rlo) * 64 + swz;            // + mi*1024 + kh*32768
    int bb = 16384 + (wn * 64 + rlo) * 64 + swz;     // + ni*1024 + kh*32768

    // staging source pointers (pre-swizzled global, rule #21)
    int r0 = tid >> 2;
    int ps = tid & 3;
    int ssw = (ps ^ ((r0 >> 1) & 3)) * 8;
    const us* pA = A + (size_t)(m0 + r0) * KX + ssw;
    const us* pB = B + (size_t)(n0 + r0) * KX + ssw;
    char* lw0 = smem + w * 1024;
    char* lw1 = lw0 + 65536;
    const char* sm0 = smem;
    const char* sm1 = smem + 65536;

    floatx4 acc[8][4];
#pragma unroll
    for (int mi = 0; mi < 8; ++mi)
#pragma unroll
        for (int ni = 0; ni < 4; ++ni) acc[mi][ni] = (floatx4)0.f;

    // prologue: 7 halves (tile0 complete; tile1 A.K0,B.K0,B.K1)
    stage2<KX>(pA,      lw0);
    stage2<KX>(pB,      lw0 + 16384);
    stage2<KX>(pA + 32, lw0 + 32768);
    stage2<KX>(pB + 32, lw0 + 49152);
    stage2<KX>(pA + 64, lw1);
    stage2<KX>(pB + 64, lw1 + 16384);
    stage2<KX>(pB + 96, lw1 + 49152);
    asm volatile("s_waitcnt vmcnt(10)" ::: "memory");
    __builtin_amdgcn_s_barrier();

    short8 afA[4], afB[4], bfA[4], bfB[4];
#pragma unroll
    for (int i = 0; i < 4; ++i) afA[i] = *(const short8*)(sm0 + ab + i * 1024);
#pragma unroll
    for (int i = 0; i < 4; ++i) bfA[i] = *(const short8*)(sm0 + bb + i * 1024);

    for (int tt = 0; tt < NT / 2 - 1; ++tt) {
        int t0 = tt * 2;
        ktile<KX, 0xF, 8, 8, true>(pA, pB, (t0 + 1) * 64, (t0 + 2) * 64,
                                   sm0, sm1, lw0, lw1, ab, bb, afA, afB, bfA, bfB, acc);
        ktile<KX, 0xF, 8, 8, true>(pA, pB, (t0 + 2) * 64, (t0 + 3) * 64,
                                   sm1, sm0, lw1, lw0, ab, bb, afA, afB, bfA, bfB, acc);
    }
    ktile<KX, 0x1, 8, 4, true>(pA, pB, (NT - 1) * 64, NT * 64,
                               sm0, sm1, lw0, lw1, ab, bb, afA, afB, bfA, bfB, acc);
    ktile<KX, 0x0, 0, -1, false>(pA, pB, 0, 0,
                                 sm1, sm0, lw1, lw0, ab, bb, afA, afB, bfA, bfB, acc);

    // epilogue: C/D map col=rlo, row=kq*4+reg
    float bbias[4];
#pragma unroll
    for (int ni = 0; ni < 4; ++ni) bbias[ni] = bias[n0 + wn * 64 + ni * 16 + rlo];
#pragma unroll
    for (int mi = 0; mi < 8; ++mi) {
        int row = m0 + wm * 128 + mi * 16 + kq * 4;
#pragma unroll
        for (int ni = 0; ni < 4; ++ni) {
            int col = n0 + wn * 64 + ni * 16 + rlo;
#pragma unroll
            for (int r = 0; r < 4; ++r)
                out[(size_t)(row + r) * OUT_DIM + col] = acc[mi][ni][r] + bbias[ni];
        }
    }
}

// ===========================================================================
// combo (R16): single prep launch, no tiny_prep dependency.
//  blocks 0..255  : delta GEMM — Bext[b][n][i] = bf16(W + Bcat·diag(rw_b)·Acat^T)
//    · af (scaled Bcat cols) staged per-block into LDS slot-major sB[12][256][8]
//      (48KB; 16B/lane contiguous per 16-lane group -> 2-way aliasing = free)
//      via coalesced per-k column reads of Bs/Be (same bf16 values tiny_prep made)
//    · bf (Acat rows) loaded DIRECTLY from As/Ae: fragment k-range ks*32+kq*8..+7
//      aligns exactly with one rank-8 block -> one float4x2 per fragment
//    · R14/R15-verified LDS-transpose epilogue (coalesced 64B Bext stores)
//  blocks 256..767: x rows -> bf16 panel Aext [8192][2048]
// Dynamic LDS 66KB (sB 48K + tr 18.4K) -> 2 blocks/CU.
// ===========================================================================
__global__ __launch_bounds__(512) void combo(
    const float* __restrict__ x, const float* __restrict__ W,
    const float* __restrict__ As, const float* __restrict__ Ae,
    const float* __restrict__ Bs, const float* __restrict__ Be,
    const float* __restrict__ rw,
    us* __restrict__ Aext, us* __restrict__ Bext)
{
    extern __shared__ char dsm[];
    int bid = blockIdx.x;
    int tid = threadIdx.x;

    if (bid >= 256) {
        // ---- x -> bf16 panel, 16 rows/block ----
        int xb = bid - 256;
        int half = tid >> 8;
        int col = (tid & 255) * 8;
#pragma unroll 8
        for (int pass = 0; pass < 8; ++pass) {
            int row = xb * 16 + pass * 2 + half;
            const float4* src = (const float4*)(x + (size_t)row * IN_DIM + col);
            *(short8*)(Aext + (size_t)row * IN_DIM + col) = cvt8(src[0], src[1]);
        }
        return;
    }

    us* sB = (us*)dsm;                                  // [12][256][8]
    us (*tr)[16][72] = (us(*)[16][72])(dsm + 49152);    // [8][16][72]

    int lane = tid & 63, w = tid >> 6;
    int wm = w >> 2, wn = w & 3;           // wave-tile: 128 (n) x 64 (i)
    int rlo = lane & 15, kq = lane >> 4;
    int b = bid >> 6;
    int t6 = bid & 63;
    int nn0 = (t6 >> 3) * 256, ii0 = (t6 & 7) * 256;

    // ---- prologue: stage scaled Bcat slice into sB ----
    {
        float er[8];
#pragma unroll
        for (int e = 0; e < 8; ++e) er[e] = rw[b * NE + e];
        int r = tid >> 1, h = tid & 1;
        int n = nn0 + r;
#pragma unroll
        for (int jj = 0; jj < 6; ++jj) {
            int j = h * 6 + jj;                       // slot 0..11
            short8 v;
#pragma unroll
            for (int kk = 0; kk < 8; ++kk) {
                int k = j * 8 + kk;
                float val = 0.f;
                if (k < 8)       val = Bs[(size_t)k * OUT_DIM + n];
                else if (k < 72) val = Be[(size_t)(k - 8) * OUT_DIM + n] * er[(k - 8) >> 3];
                v[kk] = (short)f2bf(val);
            }
            *(short8*)(sB + (size_t)j * 2048 + r * 8) = v;
        }
    }
    __syncthreads();

    floatx4 acc[8][4];
#pragma unroll
    for (int mi = 0; mi < 8; ++mi)
#pragma unroll
        for (int ni = 0; ni < 4; ++ni) acc[mi][ni] = (floatx4)0.f;

#pragma unroll
    for (int ks = 0; ks < 3; ++ks) {
        short8 af[8], bf[4];
#pragma unroll
        for (int mi = 0; mi < 8; ++mi)
            af[mi] = *(const short8*)(sB + (size_t)(ks * 4 + kq) * 2048
                                         + (wm * 128 + mi * 16 + rlo) * 8);
#pragma unroll
        for (int ni = 0; ni < 4; ++ni) {
            int i = ii0 + wn * 64 + ni * 16 + rlo;
            short8 bfv = (short8)0;
            if (ks == 0) {
                const float* src = (kq == 0) ? As + (size_t)i * 8
                                             : Ae + ((size_t)(kq - 1) * IN_DIM + i) * 8;
                bfv = cvt8(((const float4*)src)[0], ((const float4*)src)[1]);
            } else if (ks == 1) {
                const float* src = Ae + ((size_t)(kq + 3) * IN_DIM + i) * 8;
                bfv = cvt8(((const float4*)src)[0], ((const float4*)src)[1]);
            } else {
                if (kq == 0) {
                    const float* src = Ae + ((size_t)7 * IN_DIM + i) * 8;
                    bfv = cvt8(((const float4*)src)[0], ((const float4*)src)[1]);
                }
            }
            bf[ni] = bfv;
        }
#pragma unroll
        for (int mi = 0; mi < 8; ++mi)
#pragma unroll
            for (int ni = 0; ni < 4; ++ni)
                acc[mi][ni] = __builtin_amdgcn_mfma_f32_16x16x32_bf16(
                    af[mi], bf[ni], acc[mi][ni], 0, 0, 0);
    }

    // epilogue via LDS transpose (R14/R15 verified); wave-local
    int icol = ii0 + wn * 64;
    int rr = lane >> 2, sl = lane & 3;
#pragma unroll
    for (int mi = 0; mi < 8; ++mi) {
        int n_base = nn0 + wm * 128 + mi * 16;
#pragma unroll
        for (int ni = 0; ni < 4; ++ni)
#pragma unroll
            for (int r = 0; r < 4; ++r) {
                int row = kq * 4 + r;
                float val = acc[mi][ni][r]
                          + W[(size_t)(n_base + row) * IN_DIM + icol + ni * 16 + rlo];
                tr[w][row][ni * 16 + rlo] = f2bf(val);
            }
        asm volatile("s_waitcnt lgkmcnt(0)" ::: "memory");
#pragma unroll
        for (int p = 0; p < 2; ++p) {
            int c0 = (sl + p * 4) * 8;
            short8 v = *(const short8*)&tr[w][rr][c0];
            *(short8*)&Bext[((size_t)b * OUT_DIM + n_base + rr) * IN_DIM + icol + c0] = v;
        }
        asm volatile("s_waitcnt lgkmcnt(0)" ::: "memory");
    }
}

// ===========================================================================
// FALLBACK PATH (exact R6, proven) — used only if ws too small.
// ===========================================================================
#define K_EXT1 2176
#define RANK_PAD 128

__global__ void prep_wb_fb(const float* __restrict__ W, const float* __restrict__ Bs,
                           const float* __restrict__ Be, const float* __restrict__ As,
                           const float* __restrict__ Ae, us* __restrict__ Bext,
                           us* __restrict__ AcatT) {
    int blk = blockIdx.x;
    int t = threadIdx.x;
    if (blk < OUT_DIM) {
        int n = blk;
        const float4* src = (const float4*)(W + (size_t)n * IN_DIM + t * 8);
        *(short8*)(Bext + (size_t)n * K_EXT1 + t * 8) = cvt8(src[0], src[1]);
        if (t < RANK_PAD) {
            float v = 0.f;
            if (t < 8)       v = Bs[(size_t)t * OUT_DIM + n];
            else if (t < 72) v = Be[(size_t)(t - 8) * OUT_DIM + n];
            Bext[(size_t)n * K_EXT1 + IN_DIM + t] = f2bf(v);
        }
    } else {
        int kp = blk - OUT_DIM;
        int i0 = t * 8;
        short8 o;
#pragma unroll
        for (int j = 0; j < 8; ++j) {
            int i = i0 + j;
            float v = 0.f;
            if (kp < 8)       v = As[(size_t)i * 8 + kp];
            else if (kp < 72) v = Ae[(size_t)((kp - 8) >> 3) * IN_DIM * 8 + (size_t)i * 8 + ((kp - 8) & 7)];
            o[j] = (short)f2bf(v);
        }
        *(short8*)(AcatT + (size_t)kp * IN_DIM + i0) = o;
    }
}

__global__ __launch_bounds__(512) void tgemm_fused_fb(const float* __restrict__ x,
                                                      us* __restrict__ Aext,
                                                      const us* __restrict__ AcatT,
                                                      const float* __restrict__ routing) {
    __shared__ floatx4 red[8][64][6];
    int tid = threadIdx.x;
    int lane = tid & 63, w = tid >> 6;
    int rlo = lane & 15, kq = lane >> 4;
    int mbase = blockIdx.x * 16;

    floatx4 acc[6];
#pragma unroll
    for (int ni = 0; ni < 6; ++ni) acc[ni] = (floatx4)0.f;

    const float* xrow = x + (size_t)(mbase + rlo) * IN_DIM + w * 256 + kq * 8;
    us* arow = Aext + (size_t)(mbase + rlo) * K_EXT1 + w * 256 + kq * 8;
    const us* bbase = AcatT + (size_t)rlo * IN_DIM + w * 256 + kq * 8;

#pragma unroll
    for (int kt = 0; kt < 8; ++kt) {
        int k0 = kt * 32;
        float4 v0 = *(const float4*)(xrow + k0);
        float4 v1 = *(const float4*)(xrow + k0 + 4);
        short8 a = cvt8(v0, v1);
        *(short8*)(arow + k0) = a;
#pragma unroll
        for (int ni = 0; ni < 6; ++ni) {
            short8 bfr = *(const short8*)(bbase + (size_t)(ni * 16) * IN_DIM + k0);
            acc[ni] = __builtin_amdgcn_mfma_f32_16x16x32_bf16(a, bfr, acc[ni], 0, 0, 0);
        }
    }

#pragma unroll
    for (int ni = 0; ni < 6; ++ni) red[w][lane][ni] = acc[ni];
    __syncthreads();
    if (w == 0) {
#pragma unroll
        for (int ni = 0; ni < 6; ++ni) {
            floatx4 s = red[0][lane][ni];
#pragma unroll
            for (int ww = 1; ww < 8; ++ww) s += red[ww][lane][ni];
            int col = ni * 16 + rlo;
#pragma unroll
            for (int r = 0; r < 4; ++r) {
                int row = mbase + kq * 4 + r;
                float fac = (col < 8) ? 1.f
                          : (col < 72 ? routing[(row >> 11) * NE + ((col - 8) >> 3)] : 0.f);
                Aext[(size_t)row * K_EXT1 + IN_DIM + col] = f2bf(s[r] * fac);
            }
        }
#pragma unroll
        for (int c = 0; c < 2; ++c) {
            int col = 96 + c * 16 + rlo;
#pragma unroll
            for (int r = 0; r < 4; ++r)
                Aext[(size_t)(mbase + kq * 4 + r) * K_EXT1 + IN_DIM + col] = 0;
        }
    }
}

// ===========================================================================
extern "C" void kernel_launch(void* const* d_in, const int* in_sizes, int n_in,
                              void* d_out, int out_size, void* d_ws, size_t ws_size,
                              hipStream_t stream) {
    const float* x   = (const float*)d_in[0];
    const float* rw  = (const float*)d_in[1];
    const float* W   = (const float*)d_in[2];
    const float* bv  = (const float*)d_in[3];
    const float* As  = (const float*)d_in[4];
    const float* Bs  = (const float*)d_in[5];
    const float* Ae  = (const float*)d_in[6];
    const float* Be  = (const float*)d_in[7];
    float* out = (float*)d_out;

    // primary layout
    size_t pA  = 0;                                               // Aext  [8192][2048] bf16
    size_t pB  = pA + (size_t)M_TOT * IN_DIM * 2;                 // Bext  [4][2048][2048] bf16
    size_t need2 = pB + (size_t)NB * OUT_DIM * IN_DIM * 2;        // ~67.1 MB

    if (ws_size >= need2) {
        us* Aext = (us*)((char*)d_ws + pA);
        us* Bext = (us*)((char*)d_ws + pB);

        hipFuncSetAttribute((const void*)&main_gemm_t<2048, true>,
                            hipFuncAttributeMaxDynamicSharedMemorySize, 131072);
        hipFuncSetAttribute((const void*)combo,
                            hipFuncAttributeMaxDynamicSharedMemorySize, 67584);

        combo<<<768, 512, 67584, stream>>>(x, W, As, Ae, Bs, Be, rw, Aext, Bext);
        main_gemm_t<2048, true><<<256, 512, 131072, stream>>>(Aext, Bext, bv, out);
        return;
    }

    // fallback: proven R6 path (K=2176 concat)
    size_t fA = 0;
    size_t fB = fA + (size_t)M_TOT * K_EXT1 * 2;
    size_t fC = fB + (size_t)OUT_DIM * K_EXT1 * 2;
    size_t need1 = fC + (size_t)96 * IN_DIM * 2;
    if (ws_size < need1) return;

    us* Aext  = (us*)((char*)d_ws + fA);
    us* Bext  = (us*)((char*)d_ws + fB);
    us* AcatT = (us*)((char*)d_ws + fC);

    hipFuncSetAttribute((const void*)&main_gemm_t<2176, false>,
                        hipFuncAttributeMaxDynamicSharedMemorySize, 131072);

    prep_wb_fb<<<OUT_DIM + 96, 256, 0, stream>>>(W, Bs, Be, As, Ae, Bext, AcatT);
    tgemm_fused_fb<<<M_TOT / 16, 512, 0, stream>>>(x, Aext, AcatT, rw);
    main_gemm_t<2176, false><<<256, 512, 131072, stream>>>(Aext, Bext, bv, out);
}

// Round 17
// 109.644 us; speedup vs baseline: 1.0158x; 1.0158x over previous
//
#include <hip/hip_runtime.h>
#include <hip/hip_bf16.h>

#define IN_DIM 2048
#define OUT_DIM 2048
#define NE 8
#define M_TOT 8192          // B*S = 4*2048
#define NB 4                // batches
#define RK 96               // 8 shared + 64 expert + 24 zero pad (K of delta GEMM)

typedef short short8 __attribute__((ext_vector_type(8)));
typedef float floatx4 __attribute__((ext_vector_type(4)));
typedef unsigned short us;

__device__ __forceinline__ us f2bf(float f) {
    __hip_bfloat16 h = __float2bfloat16(f);   // native RNE cast
    return *reinterpret_cast<us*>(&h);
}

__device__ __forceinline__ short8 cvt8(float4 v0, float4 v1) {
    short8 o;
    o[0] = (short)f2bf(v0.x); o[1] = (short)f2bf(v0.y);
    o[2] = (short)f2bf(v0.z); o[3] = (short)f2bf(v0.w);
    o[4] = (short)f2bf(v1.x); o[5] = (short)f2bf(v1.y);
    o[6] = (short)f2bf(v1.z); o[7] = (short)f2bf(v1.w);
    return o;
}

__device__ __forceinline__ void gld_lds16(const void* g, void* l) {
    __builtin_amdgcn_global_load_lds(
        (const __attribute__((address_space(1))) void*)g,
        (__attribute__((address_space(3))) void*)l, 16, 0, 0);
}

// ===========================================================================
// Main GEMM — FROZEN proven kernel (R4 schedule + XCD-chunked mapping:
// 67.1us, FETCH 49MB, 0 conflicts). Do not touch.
// ===========================================================================

template <int KX>
__device__ __forceinline__ void stage2(const us* src, char* lds) {
    gld_lds16(src, lds);
    gld_lds16(src + 128 * KX, lds + 8192);
}

__device__ __forceinline__ void mfma_quad(floatx4 (&acc)[8][4], const short8 (&af)[4],
                                          const short8 (&bf)[4], int mq) {
#pragma unroll
    for (int i = 0; i < 4; ++i)
#pragma unroll
        for (int ni = 0; ni < 4; ++ni)
            acc[mq * 4 + i][ni] =
                __builtin_amdgcn_mfma_f32_16x16x32_bf16(af[i], bf[ni], acc[mq * 4 + i][ni], 0, 0, 0);
}

template <int KX, int SM, int VM0, int VM2, bool RD3>
__device__ __forceinline__ void ktile(
    const us* __restrict__ pA, const us* __restrict__ pB, int k1, int k2,
    const char* smC, const char* smN, char* lwC, char* lwN,
    int ab, int bb,
    short8 (&afA)[4], short8 (&afB)[4], short8 (&bfA)[4], short8 (&bfB)[4],
    floatx4 (&acc)[8][4])
{
    // ---------- p0 ----------
#pragma unroll
    for (int i = 0; i < 4; ++i) afB[i] = *(const short8*)(smC + ab + (4 + i) * 1024);
    asm volatile("s_waitcnt lgkmcnt(4)" ::: "memory");
    __builtin_amdgcn_sched_barrier(0);
    __builtin_amdgcn_s_setprio(1);
    mfma_quad(acc, afA, bfA, 0);
    __builtin_amdgcn_s_setprio(0);
    if (SM & 1) stage2<KX>(pA + k1 + 32, lwN + 32768);
    if (VM0 == 8)      asm volatile("s_waitcnt vmcnt(8)" ::: "memory");
    else if (VM0 == 0) asm volatile("s_waitcnt vmcnt(0)" ::: "memory");
    __builtin_amdgcn_s_barrier();

    // ---------- p1 ----------
#pragma unroll
    for (int i = 0; i < 4; ++i) afA[i] = *(const short8*)(smC + 32768 + ab + (4 + i) * 1024);
#pragma unroll
    for (int i = 0; i < 4; ++i) bfB[i] = *(const short8*)(smC + 32768 + bb + i * 1024);
    asm volatile("s_waitcnt lgkmcnt(8)" ::: "memory");
    __builtin_amdgcn_sched_barrier(0);
    __builtin_amdgcn_s_setprio(1);
    mfma_quad(acc, afB, bfA, 1);
    __builtin_amdgcn_s_setprio(0);
    if (SM & 2) stage2<KX>(pB + k2, lwC + 16384);
    __builtin_amdgcn_s_barrier();

    // ---------- p2 ----------
#pragma unroll
    for (int i = 0; i < 4; ++i) afB[i] = *(const short8*)(smC + 32768 + ab + i * 1024);
    asm volatile("s_waitcnt lgkmcnt(4)" ::: "memory");
    __builtin_amdgcn_sched_barrier(0);
    __builtin_amdgcn_s_setprio(1);
    mfma_quad(acc, afA, bfB, 1);
    __builtin_amdgcn_s_setprio(0);
    if (SM & 4) stage2<KX>(pA + k2, lwC);
    if (VM2 == 8)      asm volatile("s_waitcnt vmcnt(8)" ::: "memory");
    else if (VM2 == 4) asm volatile("s_waitcnt vmcnt(4)" ::: "memory");
    __builtin_amdgcn_s_barrier();

    // ---------- p3 ----------
    if (RD3) {
#pragma unroll
        for (int i = 0; i < 4; ++i) afA[i] = *(const short8*)(smN + ab + i * 1024);
#pragma unroll
        for (int i = 0; i < 4; ++i) bfA[i] = *(const short8*)(smN + bb + i * 1024);
        asm volatile("s_waitcnt lgkmcnt(8)" ::: "memory");
    } else {
        asm volatile("s_waitcnt lgkmcnt(0)" ::: "memory");
    }
    __builtin_amdgcn_sched_barrier(0);
    __builtin_amdgcn_s_setprio(1);
    mfma_quad(acc, afB, bfB, 0);
    __builtin_amdgcn_s_setprio(0);
    if (SM & 8) stage2<KX>(pB + k2 + 32, lwC + 49152);
    __builtin_amdgcn_s_barrier();
}

template <int KX, bool PB>
__global__ __launch_bounds__(512) void main_gemm_t(const us* __restrict__ A,
                                                   const us* __restrict__ Bw,
                                                   const float* __restrict__ bias,
                                                   float* __restrict__ out) {
    extern __shared__ char smem[];
    constexpr int NT = KX / 64;            // 32 or 34 K-tiles
    int tid = threadIdx.x;
    int lane = tid & 63, w = tid >> 6;
    int wm = w >> 2, wn = w & 3;           // 2M x 4N waves; per-wave C = 128x64
    int rlo = lane & 15, kq = lane >> 4;

    // XCD-chunked swizzle (proven): 256 blocks = 8 XCDs x 32 contiguous
    int b = blockIdx.x;
    int bs = (b & 7) * 32 + (b >> 3);
    int m0 = (bs >> 3) * 256, n0 = (bs & 7) * 256;

    const us* B = PB ? (Bw + (size_t)(m0 >> 11) * OUT_DIM * KX) : Bw;

    int swz = (kq ^ ((rlo >> 1) & 3)) * 16;
    int ab = (wm * 128 + rlo) * 64 + swz;            // + mi*1024 + kh*32768
    int bb = 16384 + (wn * 64 + rlo) * 64 + swz;     // + ni*1024 + kh*32768

    // staging source pointers (pre-swizzled global, rule #21)
    int r0 = tid >> 2;
    int ps = tid & 3;
    int ssw = (ps ^ ((r0 >> 1) & 3)) * 8;
    const us* pA = A + (size_t)(m0 + r0) * KX + ssw;
    const us* pB = B + (size_t)(n0 + r0) * KX + ssw;
    char* lw0 = smem + w * 1024;
    char* lw1 = lw0 + 65536;
    const char* sm0 = smem;
    const char* sm1 = smem + 65536;

    floatx4 acc[8][4];
#pragma unroll
    for (int mi = 0; mi < 8; ++mi)
#pragma unroll
        for (int ni = 0; ni < 4; ++ni) acc[mi][ni] = (floatx4)0.f;

    // prologue: 7 halves (tile0 complete; tile1 A.K0,B.K0,B.K1)
    stage2<KX>(pA,      lw0);
    stage2<KX>(pB,      lw0 + 16384);
    stage2<KX>(pA + 32, lw0 + 32768);
    stage2<KX>(pB + 32, lw0 + 49152);
    stage2<KX>(pA + 64, lw1);
    stage2<KX>(pB + 64, lw1 + 16384);
    stage2<KX>(pB + 96, lw1 + 49152);
    asm volatile("s_waitcnt vmcnt(10)" ::: "memory");
    __builtin_amdgcn_s_barrier();

    short8 afA[4], afB[4], bfA[4], bfB[4];
#pragma unroll
    for (int i = 0; i < 4; ++i) afA[i] = *(const short8*)(sm0 + ab + i * 1024);
#pragma unroll
    for (int i = 0; i < 4; ++i) bfA[i] = *(const short8*)(sm0 + bb + i * 1024);

    for (int tt = 0; tt < NT / 2 - 1; ++tt) {
        int t0 = tt * 2;
        ktile<KX, 0xF, 8, 8, true>(pA, pB, (t0 + 1) * 64, (t0 + 2) * 64,
                                   sm0, sm1, lw0, lw1, ab, bb, afA, afB, bfA, bfB, acc);
        ktile<KX, 0xF, 8, 8, true>(pA, pB, (t0 + 2) * 64, (t0 + 3) * 64,
                                   sm1, sm0, lw1, lw0, ab, bb, afA, afB, bfA, bfB, acc);
    }
    ktile<KX, 0x1, 8, 4, true>(pA, pB, (NT - 1) * 64, NT * 64,
                               sm0, sm1, lw0, lw1, ab, bb, afA, afB, bfA, bfB, acc);
    ktile<KX, 0x0, 0, -1, false>(pA, pB, 0, 0,
                                 sm1, sm0, lw1, lw0, ab, bb, afA, afB, bfA, bfB, acc);

    // epilogue: C/D map col=rlo, row=kq*4+reg
    float bbias[4];
#pragma unroll
    for (int ni = 0; ni < 4; ++ni) bbias[ni] = bias[n0 + wn * 64 + ni * 16 + rlo];
#pragma unroll
    for (int mi = 0; mi < 8; ++mi) {
        int row = m0 + wm * 128 + mi * 16 + kq * 4;
#pragma unroll
        for (int ni = 0; ni < 4; ++ni) {
            int col = n0 + wn * 64 + ni * 16 + rlo;
#pragma unroll
            for (int r = 0; r < 4; ++r)
                out[(size_t)(row + r) * OUT_DIM + col] = acc[mi][ni][r] + bbias[ni];
        }
    }
}

// ===========================================================================
// tiny_prep (R13 verbatim): blocks 0..31: AcatI rows; blocks 32..39: BcatT.
// ===========================================================================
__global__ __launch_bounds__(256) void tiny_prep(
    const float* __restrict__ As, const float* __restrict__ Ae,
    const float* __restrict__ Bs, const float* __restrict__ Be,
    const float* __restrict__ rw, us* __restrict__ AcatI, us* __restrict__ BcatT)
{
    int bid = blockIdx.x;
    int tid = threadIdx.x;
    if (bid < 32) {
        if (tid < 64) {
            int r = bid * 64 + tid;
            us* dst = AcatI + (size_t)r * RK;
            const float4* as = (const float4*)(As + (size_t)r * 8);
            *(short8*)dst = cvt8(as[0], as[1]);
#pragma unroll
            for (int e = 0; e < 8; ++e) {
                const float4* ae = (const float4*)(Ae + ((size_t)e * IN_DIM + r) * 8);
                *(short8*)(dst + 8 + e * 8) = cvt8(ae[0], ae[1]);
            }
            short8 z = (short8)0;
            *(short8*)(dst + 72) = z; *(short8*)(dst + 80) = z; *(short8*)(dst + 88) = z;
        }
    } else {
        int n = (bid - 32) * 256 + tid;        // 0..2047
        float com[72];
#pragma unroll
        for (int rp = 0; rp < 8; ++rp)  com[rp] = Bs[(size_t)rp * OUT_DIM + n];
#pragma unroll
        for (int rp = 8; rp < 72; ++rp) com[rp] = Be[(size_t)(rp - 8) * OUT_DIM + n];
#pragma unroll
        for (int bb = 0; bb < NB; ++bb) {
            us v[RK];
#pragma unroll
            for (int rp = 0; rp < 8; ++rp)  v[rp] = f2bf(com[rp]);
#pragma unroll
            for (int rp = 8; rp < 72; ++rp) v[rp] = f2bf(com[rp] * rw[bb * NE + ((rp - 8) >> 3)]);
#pragma unroll
            for (int rp = 72; rp < 96; ++rp) v[rp] = 0;
            us* dst = BcatT + ((size_t)bb * OUT_DIM + n) * RK;
#pragma unroll
            for (int j = 0; j < 12; ++j)
                *(short8*)(dst + j * 8) = *(short8*)(v + j * 8);
        }
    }
}

// ===========================================================================
// combo (R15): blocks 0..255 : delta GEMM with R14-verified LDS-transpose
//              epilogue (coalesced 64B Bext stores).
//              blocks 256..767: x rows -> bf16 panel Aext [8192][2048].
// Roles overlap: delta's MFMA+write stream runs under the x read stream.
// ===========================================================================
__global__ __launch_bounds__(512) void combo(
    const float* __restrict__ x, const float* __restrict__ W,
    const us* __restrict__ AcatI, const us* __restrict__ BcatT,
    us* __restrict__ Aext, us* __restrict__ Bext)
{
    __shared__ us tr[8][16][72];
    int bid = blockIdx.x;
    int tid = threadIdx.x;

    if (bid >= 256) {
        // ---- x -> bf16 panel, 16 rows/block ----
        int xb = bid - 256;
        int half = tid >> 8;
        int col = (tid & 255) * 8;
#pragma unroll 8
        for (int pass = 0; pass < 8; ++pass) {
            int row = xb * 16 + pass * 2 + half;
            const float4* src = (const float4*)(x + (size_t)row * IN_DIM + col);
            *(short8*)(Aext + (size_t)row * IN_DIM + col) = cvt8(src[0], src[1]);
        }
        return;
    }

    // ---- delta GEMM (math identical to R11; R14-verified transposed epilogue) ----
    int lane = tid & 63, w = tid >> 6;
    int wm = w >> 2, wn = w & 3;           // wave-tile: 128 (n) x 64 (i)
    int rlo = lane & 15, kq = lane >> 4;
    int b = bid >> 6;
    int t6 = bid & 63;
    int nn0 = (t6 >> 3) * 256, ii0 = (t6 & 7) * 256;

    const us* bct = BcatT + ((size_t)b * OUT_DIM + nn0 + wm * 128 + rlo) * RK + kq * 8;
    const us* aci = AcatI + ((size_t)(ii0 + wn * 64 + rlo)) * RK + kq * 8;

    floatx4 acc[8][4];
#pragma unroll
    for (int mi = 0; mi < 8; ++mi)
#pragma unroll
        for (int ni = 0; ni < 4; ++ni) acc[mi][ni] = (floatx4)0.f;

#pragma unroll
    for (int ks = 0; ks < 3; ++ks) {
        int k0 = ks * 32;
        short8 af[8], bf[4];
#pragma unroll
        for (int mi = 0; mi < 8; ++mi)
            af[mi] = *(const short8*)(bct + (size_t)mi * 16 * RK + k0);
#pragma unroll
        for (int ni = 0; ni < 4; ++ni)
            bf[ni] = *(const short8*)(aci + (size_t)ni * 16 * RK + k0);
#pragma unroll
        for (int mi = 0; mi < 8; ++mi)
#pragma unroll
            for (int ni = 0; ni < 4; ++ni)
                acc[mi][ni] = __builtin_amdgcn_mfma_f32_16x16x32_bf16(
                    af[mi], bf[ni], acc[mi][ni], 0, 0, 0);
    }

    // epilogue via LDS transpose; wave-local, no cross-wave sync needed
    int icol = ii0 + wn * 64;
    int rr = lane >> 2, sl = lane & 3;
#pragma unroll
    for (int mi = 0; mi < 8; ++mi) {
        int n_base = nn0 + wm * 128 + mi * 16;
#pragma unroll
        for (int ni = 0; ni < 4; ++ni)
#pragma unroll
            for (int r = 0; r < 4; ++r) {
                int row = kq * 4 + r;
                float val = acc[mi][ni][r]
                          + W[(size_t)(n_base + row) * IN_DIM + icol + ni * 16 + rlo];
                tr[w][row][ni * 16 + rlo] = f2bf(val);
            }
        asm volatile("s_waitcnt lgkmcnt(0)" ::: "memory");
#pragma unroll
        for (int p = 0; p < 2; ++p) {
            int c0 = (sl + p * 4) * 8;
            short8 v = *(const short8*)&tr[w][rr][c0];
            *(short8*)&Bext[((size_t)b * OUT_DIM + n_base + rr) * IN_DIM + icol + c0] = v;
        }
        asm volatile("s_waitcnt lgkmcnt(0)" ::: "memory");
    }
}

// ===========================================================================
// FALLBACK PATH (exact R6, proven) — used only if ws too small.
// ===========================================================================
#define K_EXT1 2176
#define RANK_PAD 128

__global__ void prep_wb_fb(const float* __restrict__ W, const float* __restrict__ Bs,
                           const float* __restrict__ Be, const float* __restrict__ As,
                           const float* __restrict__ Ae, us* __restrict__ Bext,
                           us* __restrict__ AcatT) {
    int blk = blockIdx.x;
    int t = threadIdx.x;
    if (blk < OUT_DIM) {
        int n = blk;
        const float4* src = (const float4*)(W + (size_t)n * IN_DIM + t * 8);
        *(short8*)(Bext + (size_t)n * K_EXT1 + t * 8) = cvt8(src[0], src[1]);
        if (t < RANK_PAD) {
            float v = 0.f;
            if (t < 8)       v = Bs[(size_t)t * OUT_DIM + n];
            else if (t < 72) v = Be[(size_t)(t - 8) * OUT_DIM + n];
            Bext[(size_t)n * K_EXT1 + IN_DIM + t] = f2bf(v);
        }
    } else {
        int kp = blk - OUT_DIM;
        int i0 = t * 8;
        short8 o;
#pragma unroll
        for (int j = 0; j < 8; ++j) {
            int i = i0 + j;
            float v = 0.f;
            if (kp < 8)       v = As[(size_t)i * 8 + kp];
            else if (kp < 72) v = Ae[(size_t)((kp - 8) >> 3) * IN_DIM * 8 + (size_t)i * 8 + ((kp - 8) & 7)];
            o[j] = (short)f2bf(v);
        }
        *(short8*)(AcatT + (size_t)kp * IN_DIM + i0) = o;
    }
}

__global__ __launch_bounds__(512) void tgemm_fused_fb(const float* __restrict__ x,
                                                      us* __restrict__ Aext,
                                                      const us* __restrict__ AcatT,
                                                      const float* __restrict__ routing) {
    __shared__ floatx4 red[8][64][6];
    int tid = threadIdx.x;
    int lane = tid & 63, w = tid >> 6;
    int rlo = lane & 15, kq = lane >> 4;
    int mbase = blockIdx.x * 16;

    floatx4 acc[6];
#pragma unroll
    for (int ni = 0; ni < 6; ++ni) acc[ni] = (floatx4)0.f;

    const float* xrow = x + (size_t)(mbase + rlo) * IN_DIM + w * 256 + kq * 8;
    us* arow = Aext + (size_t)(mbase + rlo) * K_EXT1 + w * 256 + kq * 8;
    const us* bbase = AcatT + (size_t)rlo * IN_DIM + w * 256 + kq * 8;

#pragma unroll
    for (int kt = 0; kt < 8; ++kt) {
        int k0 = kt * 32;
        float4 v0 = *(const float4*)(xrow + k0);
        float4 v1 = *(const float4*)(xrow + k0 + 4);
        short8 a = cvt8(v0, v1);
        *(short8*)(arow + k0) = a;
#pragma unroll
        for (int ni = 0; ni < 6; ++ni) {
            short8 bfr = *(const short8*)(bbase + (size_t)(ni * 16) * IN_DIM + k0);
            acc[ni] = __builtin_amdgcn_mfma_f32_16x16x32_bf16(a, bfr, acc[ni], 0, 0, 0);
        }
    }

#pragma unroll
    for (int ni = 0; ni < 6; ++ni) red[w][lane][ni] = acc[ni];
    __syncthreads();
    if (w == 0) {
#pragma unroll
        for (int ni = 0; ni < 6; ++ni) {
            floatx4 s = red[0][lane][ni];
#pragma unroll
            for (int ww = 1; ww < 8; ++ww) s += red[ww][lane][ni];
            int col = ni * 16 + rlo;
#pragma unroll
            for (int r = 0; r < 4; ++r) {
                int row = mbase + kq * 4 + r;
                float fac = (col < 8) ? 1.f
                          : (col < 72 ? routing[(row >> 11) * NE + ((col - 8) >> 3)] : 0.f);
                Aext[(size_t)row * K_EXT1 + IN_DIM + col] = f2bf(s[r] * fac);
            }
        }
#pragma unroll
        for (int c = 0; c < 2; ++c) {
            int col = 96 + c * 16 + rlo;
#pragma unroll
            for (int r = 0; r < 4; ++r)
                Aext[(size_t)(mbase + kq * 4 + r) * K_EXT1 + IN_DIM + col] = 0;
        }
    }
}

// ===========================================================================
extern "C" void kernel_launch(void* const* d_in, const int* in_sizes, int n_in,
                              void* d_out, int out_size, void* d_ws, size_t ws_size,
                              hipStream_t stream) {
    const float* x   = (const float*)d_in[0];
    const float* rw  = (const float*)d_in[1];
    const float* W   = (const float*)d_in[2];
    const float* bv  = (const float*)d_in[3];
    const float* As  = (const float*)d_in[4];
    const float* Bs  = (const float*)d_in[5];
    const float* Ae  = (const float*)d_in[6];
    const float* Be  = (const float*)d_in[7];
    float* out = (float*)d_out;

    // primary layout
    size_t pA  = 0;                                               // Aext  [8192][2048] bf16
    size_t pB  = pA + (size_t)M_TOT * IN_DIM * 2;                 // Bext  [4][2048][2048] bf16
    size_t pAI = pB + (size_t)NB * OUT_DIM * IN_DIM * 2;          // AcatI [2048][96] bf16
    size_t pBT = pAI + (size_t)IN_DIM * RK * 2;                   // BcatT [4][2048][96] bf16
    size_t need2 = pBT + (size_t)NB * OUT_DIM * RK * 2;           // ~69.1 MB

    if (ws_size >= need2) {
        us* Aext  = (us*)((char*)d_ws + pA);
        us* Bext  = (us*)((char*)d_ws + pB);
        us* AcatI = (us*)((char*)d_ws + pAI);
        us* BcatT = (us*)((char*)d_ws + pBT);

        hipFuncSetAttribute((const void*)&main_gemm_t<2048, true>,
                            hipFuncAttributeMaxDynamicSharedMemorySize, 131072);

        tiny_prep<<<40, 256, 0, stream>>>(As, Ae, Bs, Be, rw, AcatI, BcatT);
        combo<<<768, 512, 0, stream>>>(x, W, AcatI, BcatT, Aext, Bext);
        main_gemm_t<2048, true><<<256, 512, 131072, stream>>>(Aext, Bext, bv, out);
        return;
    }

    // fallback: proven R6 path (K=2176 concat)
    size_t fA = 0;
    size_t fB = fA + (size_t)M_TOT * K_EXT1 * 2;
    size_t fC = fB + (size_t)OUT_DIM * K_EXT1 * 2;
    size_t need1 = fC + (size_t)96 * IN_DIM * 2;
    if (ws_size < need1) return;

    us* Aext  = (us*)((char*)d_ws + fA);
    us* Bext  = (us*)((char*)d_ws + fB);
    us* AcatT = (us*)((char*)d_ws + fC);

    hipFuncSetAttribute((const void*)&main_gemm_t<2176, false>,
                        hipFuncAttributeMaxDynamicSharedMemorySize, 131072);

    prep_wb_fb<<<OUT_DIM + 96, 256, 0, stream>>>(W, Bs, Be, As, Ae, Bext, AcatT);
    tgemm_fused_fb<<<M_TOT / 16, 512, 0, stream>>>(x, Aext, AcatT, rw);
    main_gemm_t<2176, false><<<256, 512, 131072, stream>>>(Aext, Bext, bv, out);
}

// Round 18
// 108.564 us; speedup vs baseline: 1.0259x; 1.0100x over previous
//
#include <hip/hip_runtime.h>
#include <hip/hip_bf16.h>

#define IN_DIM 2048
#define OUT_DIM 2048
#define NE 8
#define M_TOT 8192          // B*S = 4*2048
#define NB 4                // batches
#define RK 96               // 8 shared + 64 expert + 24 zero pad

typedef short short8 __attribute__((ext_vector_type(8)));
typedef float floatx4 __attribute__((ext_vector_type(4)));
typedef unsigned short us;

__device__ __forceinline__ us f2bf(float f) {
    __hip_bfloat16 h = __float2bfloat16(f);   // native RNE cast
    return *reinterpret_cast<us*>(&h);
}

__device__ __forceinline__ short8 cvt8(float4 v0, float4 v1) {
    short8 o;
    o[0] = (short)f2bf(v0.x); o[1] = (short)f2bf(v0.y);
    o[2] = (short)f2bf(v0.z); o[3] = (short)f2bf(v0.w);
    o[4] = (short)f2bf(v1.x); o[5] = (short)f2bf(v1.y);
    o[6] = (short)f2bf(v1.z); o[7] = (short)f2bf(v1.w);
    return o;
}

__device__ __forceinline__ void gld_lds16(const void* g, void* l) {
    __builtin_amdgcn_global_load_lds(
        (const __attribute__((address_space(1))) void*)g,
        (__attribute__((address_space(3))) void*)l, 16, 0, 0);
}

// ===========================================================================
// Main GEMM — FROZEN proven kernel (R4 schedule + XCD-chunked mapping:
// 67.1us, FETCH 49MB, 0 conflicts). Do not touch.
// ===========================================================================

template <int KX>
__device__ __forceinline__ void stage2(const us* src, char* lds) {
    gld_lds16(src, lds);
    gld_lds16(src + 128 * KX, lds + 8192);
}

__device__ __forceinline__ void mfma_quad(floatx4 (&acc)[8][4], const short8 (&af)[4],
                                          const short8 (&bf)[4], int mq) {
#pragma unroll
    for (int i = 0; i < 4; ++i)
#pragma unroll
        for (int ni = 0; ni < 4; ++ni)
            acc[mq * 4 + i][ni] =
                __builtin_amdgcn_mfma_f32_16x16x32_bf16(af[i], bf[ni], acc[mq * 4 + i][ni], 0, 0, 0);
}

template <int KX, int SM, int VM0, int VM2, bool RD3>
__device__ __forceinline__ void ktile(
    const us* __restrict__ pA, const us* __restrict__ pB, int k1, int k2,
    const char* smC, const char* smN, char* lwC, char* lwN,
    int ab, int bb,
    short8 (&afA)[4], short8 (&afB)[4], short8 (&bfA)[4], short8 (&bfB)[4],
    floatx4 (&acc)[8][4])
{
    // ---------- p0 ----------
#pragma unroll
    for (int i = 0; i < 4; ++i) afB[i] = *(const short8*)(smC + ab + (4 + i) * 1024);
    asm volatile("s_waitcnt lgkmcnt(4)" ::: "memory");
    __builtin_amdgcn_sched_barrier(0);
    __builtin_amdgcn_s_setprio(1);
    mfma_quad(acc, afA, bfA, 0);
    __builtin_amdgcn_s_setprio(0);
    if (SM & 1) stage2<KX>(pA + k1 + 32, lwN + 32768);
    if (VM0 == 8)      asm volatile("s_waitcnt vmcnt(8)" ::: "memory");
    else if (VM0 == 0) asm volatile("s_waitcnt vmcnt(0)" ::: "memory");
    __builtin_amdgcn_s_barrier();

    // ---------- p1 ----------
#pragma unroll
    for (int i = 0; i < 4; ++i) afA[i] = *(const short8*)(smC + 32768 + ab + (4 + i) * 1024);
#pragma unroll
    for (int i = 0; i < 4; ++i) bfB[i] = *(const short8*)(smC + 32768 + bb + i * 1024);
    asm volatile("s_waitcnt lgkmcnt(8)" ::: "memory");
    __builtin_amdgcn_sched_barrier(0);
    __builtin_amdgcn_s_setprio(1);
    mfma_quad(acc, afB, bfA, 1);
    __builtin_amdgcn_s_setprio(0);
    if (SM & 2) stage2<KX>(pB + k2, lwC + 16384);
    __builtin_amdgcn_s_barrier();

    // ---------- p2 ----------
#pragma unroll
    for (int i = 0; i < 4; ++i) afB[i] = *(const short8*)(smC + 32768 + ab + i * 1024);
    asm volatile("s_waitcnt lgkmcnt(4)" ::: "memory");
    __builtin_amdgcn_sched_barrier(0);
    __builtin_amdgcn_s_setprio(1);
    mfma_quad(acc, afA, bfB, 1);
    __builtin_amdgcn_s_setprio(0);
    if (SM & 4) stage2<KX>(pA + k2, lwC);
    if (VM2 == 8)      asm volatile("s_waitcnt vmcnt(8)" ::: "memory");
    else if (VM2 == 4) asm volatile("s_waitcnt vmcnt(4)" ::: "memory");
    __builtin_amdgcn_s_barrier();

    // ---------- p3 ----------
    if (RD3) {
#pragma unroll
        for (int i = 0; i < 4; ++i) afA[i] = *(const short8*)(smN + ab + i * 1024);
#pragma unroll
        for (int i = 0; i < 4; ++i) bfA[i] = *(const short8*)(smN + bb + i * 1024);
        asm volatile("s_waitcnt lgkmcnt(8)" ::: "memory");
    } else {
        asm volatile("s_waitcnt lgkmcnt(0)" ::: "memory");
    }
    __builtin_amdgcn_sched_barrier(0);
    __builtin_amdgcn_s_setprio(1);
    mfma_quad(acc, afB, bfB, 0);
    __builtin_amdgcn_s_setprio(0);
    if (SM & 8) stage2<KX>(pB + k2 + 32, lwC + 49152);
    __builtin_amdgcn_s_barrier();
}

template <int KX, bool PB>
__global__ __launch_bounds__(512) void main_gemm_t(const us* __restrict__ A,
                                                   const us* __restrict__ Bw,
                                                   const float* __restrict__ bias,
                                                   float* __restrict__ out) {
    extern __shared__ char smem[];
    constexpr int NT = KX / 64;            // 32 or 34 K-tiles
    int tid = threadIdx.x;
    int lane = tid & 63, w = tid >> 6;
    int wm = w >> 2, wn = w & 3;           // 2M x 4N waves; per-wave C = 128x64
    int rlo = lane & 15, kq = lane >> 4;

    // XCD-chunked swizzle (proven): 256 blocks = 8 XCDs x 32 contiguous
    int b = blockIdx.x;
    int bs = (b & 7) * 32 + (b >> 3);
    int m0 = (bs >> 3) * 256, n0 = (bs & 7) * 256;

    const us* B = PB ? (Bw + (size_t)(m0 >> 11) * OUT_DIM * KX) : Bw;

    int swz = (kq ^ ((rlo >> 1) & 3)) * 16;
    int ab = (wm * 128 + rlo) * 64 + swz;            // + mi*1024 + kh*32768
    int bb = 16384 + (wn * 64 + rlo) * 64 + swz;     // + ni*1024 + kh*32768

    // staging source pointers (pre-swizzled global, rule #21)
    int r0 = tid >> 2;
    int ps = tid & 3;
    int ssw = (ps ^ ((r0 >> 1) & 3)) * 8;
    const us* pA = A + (size_t)(m0 + r0) * KX + ssw;
    const us* pB = B + (size_t)(n0 + r0) * KX + ssw;
    char* lw0 = smem + w * 1024;
    char* lw1 = lw0 + 65536;
    const char* sm0 = smem;
    const char* sm1 = smem + 65536;

    floatx4 acc[8][4];
#pragma unroll
    for (int mi = 0; mi < 8; ++mi)
#pragma unroll
        for (int ni = 0; ni < 4; ++ni) acc[mi][ni] = (floatx4)0.f;

    // prologue: 7 halves (tile0 complete; tile1 A.K0,B.K0,B.K1)
    stage2<KX>(pA,      lw0);
    stage2<KX>(pB,      lw0 + 16384);
    stage2<KX>(pA + 32, lw0 + 32768);
    stage2<KX>(pB + 32, lw0 + 49152);
    stage2<KX>(pA + 64, lw1);
    stage2<KX>(pB + 64, lw1 + 16384);
    stage2<KX>(pB + 96, lw1 + 49152);
    asm volatile("s_waitcnt vmcnt(10)" ::: "memory");
    __builtin_amdgcn_s_barrier();

    short8 afA[4], afB[4], bfA[4], bfB[4];
#pragma unroll
    for (int i = 0; i < 4; ++i) afA[i] = *(const short8*)(sm0 + ab + i * 1024);
#pragma unroll
    for (int i = 0; i < 4; ++i) bfA[i] = *(const short8*)(sm0 + bb + i * 1024);

    for (int tt = 0; tt < NT / 2 - 1; ++tt) {
        int t0 = tt * 2;
        ktile<KX, 0xF, 8, 8, true>(pA, pB, (t0 + 1) * 64, (t0 + 2) * 64,
                                   sm0, sm1, lw0, lw1, ab, bb, afA, afB, bfA, bfB, acc);
        ktile<KX, 0xF, 8, 8, true>(pA, pB, (t0 + 2) * 64, (t0 + 3) * 64,
                                   sm1, sm0, lw1, lw0, ab, bb, afA, afB, bfA, bfB, acc);
    }
    ktile<KX, 0x1, 8, 4, true>(pA, pB, (NT - 1) * 64, NT * 64,
                               sm0, sm1, lw0, lw1, ab, bb, afA, afB, bfA, bfB, acc);
    ktile<KX, 0x0, 0, -1, false>(pA, pB, 0, 0,
                                 sm1, sm0, lw1, lw0, ab, bb, afA, afB, bfA, bfB, acc);

    // epilogue: C/D map col=rlo, row=kq*4+reg
    float bbias[4];
#pragma unroll
    for (int ni = 0; ni < 4; ++ni) bbias[ni] = bias[n0 + wn * 64 + ni * 16 + rlo];
#pragma unroll
    for (int mi = 0; mi < 8; ++mi) {
        int row = m0 + wm * 128 + mi * 16 + kq * 4;
#pragma unroll
        for (int ni = 0; ni < 4; ++ni) {
            int col = n0 + wn * 64 + ni * 16 + rlo;
#pragma unroll
            for (int r = 0; r < 4; ++r)
                out[(size_t)(row + r) * OUT_DIM + col] = acc[mi][ni][r] + bbias[ni];
        }
    }
}

// ===========================================================================
// combo (R18): single prep launch, NO tiny_prep dependency.
//  blocks 0..255  : delta GEMM — Bext[b][n][i] = bf16(W + Bcat·diag(rw_b)·Acat^T)
//    · af (scaled Bcat cols) staged PER-ks into static sB[4][256][8] (16KB,
//      2 short8 writes/thread/round, barrier-paired) — fixes R16's 66KB
//      dynamic-LDS occupancy kill + serial 12-slot prologue.
//    · bf (Acat rows) DIRECT from As/Ae (R16-verified: fragment k-range
//      ks*32+kq*8 aligns exactly with one rank-8 block -> one float4x2).
//    · R14/R15-verified LDS-transpose epilogue (coalesced 64B Bext stores).
//  blocks 256..767: x rows -> bf16 panel Aext [8192][2048] (R15 verbatim).
// Static LDS 34.8KB -> 3-4 blocks/CU preserved.
// ===========================================================================
__global__ __launch_bounds__(512) void combo(
    const float* __restrict__ x, const float* __restrict__ W,
    const float* __restrict__ As, const float* __restrict__ Ae,
    const float* __restrict__ Bs, const float* __restrict__ Be,
    const float* __restrict__ rw,
    us* __restrict__ Aext, us* __restrict__ Bext)
{
    __shared__ us sB[4][256][8];     // 16 KB, re-staged each ks
    __shared__ us tr[8][16][72];     // 18.4 KB
    int bid = blockIdx.x;
    int tid = threadIdx.x;

    if (bid >= 256) {
        // ---- x -> bf16 panel, 16 rows/block (R15 verbatim) ----
        int xb = bid - 256;
        int half = tid >> 8;
        int col = (tid & 255) * 8;
#pragma unroll 8
        for (int pass = 0; pass < 8; ++pass) {
            int row = xb * 16 + pass * 2 + half;
            const float4* src = (const float4*)(x + (size_t)row * IN_DIM + col);
            *(short8*)(Aext + (size_t)row * IN_DIM + col) = cvt8(src[0], src[1]);
        }
        return;
    }

    int lane = tid & 63, w = tid >> 6;
    int wm = w >> 2, wn = w & 3;           // wave-tile: 128 (n) x 64 (i)
    int rlo = lane & 15, kq = lane >> 4;
    int b = bid >> 6;
    int t6 = bid & 63;
    int nn0 = (t6 >> 3) * 256, ii0 = (t6 & 7) * 256;

    float er[8];
#pragma unroll
    for (int e = 0; e < 8; ++e) er[e] = rw[b * NE + e];

    floatx4 acc[8][4];
#pragma unroll
    for (int mi = 0; mi < 8; ++mi)
#pragma unroll
        for (int ni = 0; ni < 4; ++ni) acc[mi][ni] = (floatx4)0.f;

#pragma unroll
    for (int ks = 0; ks < 3; ++ks) {
        __syncthreads();   // protect previous round's sB reads
        // stage 4 slots (k = ks*32 .. ks*32+31) of scaled Bcat: 2 writes/thread
#pragma unroll
        for (int q = 0; q < 2; ++q) {
            int idx = q * 512 + tid;
            int r = idx & 255, jl = idx >> 8;
            int n = nn0 + r;
            int kbase = (ks * 4 + jl) * 8;
            short8 v;
#pragma unroll
            for (int kk = 0; kk < 8; ++kk) {
                int k = kbase + kk;
                float val = 0.f;
                if (k < 8)       val = Bs[(size_t)k * OUT_DIM + n];
                else if (k < 72) val = Be[(size_t)(k - 8) * OUT_DIM + n] * er[(k - 8) >> 3];
                v[kk] = (short)f2bf(val);
            }
            *(short8*)&sB[jl][r][0] = v;
        }
        __syncthreads();

        short8 af[8], bf[4];
#pragma unroll
        for (int mi = 0; mi < 8; ++mi)
            af[mi] = *(const short8*)&sB[kq][wm * 128 + mi * 16 + rlo][0];
#pragma unroll
        for (int ni = 0; ni < 4; ++ni) {
            int i = ii0 + wn * 64 + ni * 16 + rlo;
            short8 bfv = (short8)0;
            if (ks == 0) {
                const float* src = (kq == 0) ? As + (size_t)i * 8
                                             : Ae + ((size_t)(kq - 1) * IN_DIM + i) * 8;
                bfv = cvt8(((const float4*)src)[0], ((const float4*)src)[1]);
            } else if (ks == 1) {
                const float* src = Ae + ((size_t)(kq + 3) * IN_DIM + i) * 8;
                bfv = cvt8(((const float4*)src)[0], ((const float4*)src)[1]);
            } else {
                if (kq == 0) {
                    const float* src = Ae + ((size_t)7 * IN_DIM + i) * 8;
                    bfv = cvt8(((const float4*)src)[0], ((const float4*)src)[1]);
                }
            }
            bf[ni] = bfv;
        }
#pragma unroll
        for (int mi = 0; mi < 8; ++mi)
#pragma unroll
            for (int ni = 0; ni < 4; ++ni)
                acc[mi][ni] = __builtin_amdgcn_mfma_f32_16x16x32_bf16(
                    af[mi], bf[ni], acc[mi][ni], 0, 0, 0);
    }

    // epilogue via LDS transpose (R14/R15 verified); wave-local
    int icol = ii0 + wn * 64;
    int rr = lane >> 2, sl = lane & 3;
#pragma unroll
    for (int mi = 0; mi < 8; ++mi) {
        int n_base = nn0 + wm * 128 + mi * 16;
#pragma unroll
        for (int ni = 0; ni < 4; ++ni)
#pragma unroll
            for (int r = 0; r < 4; ++r) {
                int row = kq * 4 + r;
                float val = acc[mi][ni][r]
                          + W[(size_t)(n_base + row) * IN_DIM + icol + ni * 16 + rlo];
                tr[w][row][ni * 16 + rlo] = f2bf(val);
            }
        asm volatile("s_waitcnt lgkmcnt(0)" ::: "memory");
#pragma unroll
        for (int p = 0; p < 2; ++p) {
            int c0 = (sl + p * 4) * 8;
            short8 v = *(const short8*)&tr[w][rr][c0];
            *(short8*)&Bext[((size_t)b * OUT_DIM + n_base + rr) * IN_DIM + icol + c0] = v;
        }
        asm volatile("s_waitcnt lgkmcnt(0)" ::: "memory");
    }
}

// ===========================================================================
// FALLBACK PATH (exact R6, proven) — used only if ws too small.
// ===========================================================================
#define K_EXT1 2176
#define RANK_PAD 128

__global__ void prep_wb_fb(const float* __restrict__ W, const float* __restrict__ Bs,
                           const float* __restrict__ Be, const float* __restrict__ As,
                           const float* __restrict__ Ae, us* __restrict__ Bext,
                           us* __restrict__ AcatT) {
    int blk = blockIdx.x;
    int t = threadIdx.x;
    if (blk < OUT_DIM) {
        int n = blk;
        const float4* src = (const float4*)(W + (size_t)n * IN_DIM + t * 8);
        *(short8*)(Bext + (size_t)n * K_EXT1 + t * 8) = cvt8(src[0], src[1]);
        if (t < RANK_PAD) {
            float v = 0.f;
            if (t < 8)       v = Bs[(size_t)t * OUT_DIM + n];
            else if (t < 72) v = Be[(size_t)(t - 8) * OUT_DIM + n];
            Bext[(size_t)n * K_EXT1 + IN_DIM + t] = f2bf(v);
        }
    } else {
        int kp = blk - OUT_DIM;
        int i0 = t * 8;
        short8 o;
#pragma unroll
        for (int j = 0; j < 8; ++j) {
            int i = i0 + j;
            float v = 0.f;
            if (kp < 8)       v = As[(size_t)i * 8 + kp];
            else if (kp < 72) v = Ae[(size_t)((kp - 8) >> 3) * IN_DIM * 8 + (size_t)i * 8 + ((kp - 8) & 7)];
            o[j] = (short)f2bf(v);
        }
        *(short8*)(AcatT + (size_t)kp * IN_DIM + i0) = o;
    }
}

__global__ __launch_bounds__(512) void tgemm_fused_fb(const float* __restrict__ x,
                                                      us* __restrict__ Aext,
                                                      const us* __restrict__ AcatT,
                                                      const float* __restrict__ routing) {
    __shared__ floatx4 red[8][64][6];
    int tid = threadIdx.x;
    int lane = tid & 63, w = tid >> 6;
    int rlo = lane & 15, kq = lane >> 4;
    int mbase = blockIdx.x * 16;

    floatx4 acc[6];
#pragma unroll
    for (int ni = 0; ni < 6; ++ni) acc[ni] = (floatx4)0.f;

    const float* xrow = x + (size_t)(mbase + rlo) * IN_DIM + w * 256 + kq * 8;
    us* arow = Aext + (size_t)(mbase + rlo) * K_EXT1 + w * 256 + kq * 8;
    const us* bbase = AcatT + (size_t)rlo * IN_DIM + w * 256 + kq * 8;

#pragma unroll
    for (int kt = 0; kt < 8; ++kt) {
        int k0 = kt * 32;
        float4 v0 = *(const float4*)(xrow + k0);
        float4 v1 = *(const float4*)(xrow + k0 + 4);
        short8 a = cvt8(v0, v1);
        *(short8*)(arow + k0) = a;
#pragma unroll
        for (int ni = 0; ni < 6; ++ni) {
            short8 bfr = *(const short8*)(bbase + (size_t)(ni * 16) * IN_DIM + k0);
            acc[ni] = __builtin_amdgcn_mfma_f32_16x16x32_bf16(a, bfr, acc[ni], 0, 0, 0);
        }
    }

#pragma unroll
    for (int ni = 0; ni < 6; ++ni) red[w][lane][ni] = acc[ni];
    __syncthreads();
    if (w == 0) {
#pragma unroll
        for (int ni = 0; ni < 6; ++ni) {
            floatx4 s = red[0][lane][ni];
#pragma unroll
            for (int ww = 1; ww < 8; ++ww) s += red[ww][lane][ni];
            int col = ni * 16 + rlo;
#pragma unroll
            for (int r = 0; r < 4; ++r) {
                int row = mbase + kq * 4 + r;
                float fac = (col < 8) ? 1.f
                          : (col < 72 ? routing[(row >> 11) * NE + ((col - 8) >> 3)] : 0.f);
                Aext[(size_t)row * K_EXT1 + IN_DIM + col] = f2bf(s[r] * fac);
            }
        }
#pragma unroll
        for (int c = 0; c < 2; ++c) {
            int col = 96 + c * 16 + rlo;
#pragma unroll
            for (int r = 0; r < 4; ++r)
                Aext[(size_t)(mbase + kq * 4 + r) * K_EXT1 + IN_DIM + col] = 0;
        }
    }
}

// ===========================================================================
extern "C" void kernel_launch(void* const* d_in, const int* in_sizes, int n_in,
                              void* d_out, int out_size, void* d_ws, size_t ws_size,
                              hipStream_t stream) {
    const float* x   = (const float*)d_in[0];
    const float* rw  = (const float*)d_in[1];
    const float* W   = (const float*)d_in[2];
    const float* bv  = (const float*)d_in[3];
    const float* As  = (const float*)d_in[4];
    const float* Bs  = (const float*)d_in[5];
    const float* Ae  = (const float*)d_in[6];
    const float* Be  = (const float*)d_in[7];
    float* out = (float*)d_out;

    // primary layout
    size_t pA  = 0;                                               // Aext  [8192][2048] bf16
    size_t pB  = pA + (size_t)M_TOT * IN_DIM * 2;                 // Bext  [4][2048][2048] bf16
    size_t need2 = pB + (size_t)NB * OUT_DIM * IN_DIM * 2;        // ~67.1 MB

    if (ws_size >= need2) {
        us* Aext = (us*)((char*)d_ws + pA);
        us* Bext = (us*)((char*)d_ws + pB);

        hipFuncSetAttribute((const void*)&main_gemm_t<2048, true>,
                            hipFuncAttributeMaxDynamicSharedMemorySize, 131072);

        combo<<<768, 512, 0, stream>>>(x, W, As, Ae, Bs, Be, rw, Aext, Bext);
        main_gemm_t<2048, true><<<256, 512, 131072, stream>>>(Aext, Bext, bv, out);
        return;
    }

    // fallback: proven R6 path (K=2176 concat)
    size_t fA = 0;
    size_t fB = fA + (size_t)M_TOT * K_EXT1 * 2;
    size_t fC = fB + (size_t)OUT_DIM * K_EXT1 * 2;
    size_t need1 = fC + (size_t)96 * IN_DIM * 2;
    if (ws_size < need1) return;

    us* Aext  = (us*)((char*)d_ws + fA);
    us* Bext  = (us*)((char*)d_ws + fB);
    us* AcatT = (us*)((char*)d_ws + fC);

    hipFuncSetAttribute((const void*)&main_gemm_t<2176, false>,
                        hipFuncAttributeMaxDynamicSharedMemorySize, 131072);

    prep_wb_fb<<<OUT_DIM + 96, 256, 0, stream>>>(W, Bs, Be, As, Ae, Bext, AcatT);
    tgemm_fused_fb<<<M_TOT / 16, 512, 0, stream>>>(x, Aext, AcatT, rw);
    main_gemm_t<2176, false><<<256, 512, 131072, stream>>>(Aext, Bext, bv, out);
}

// Round 19
// 108.482 us; speedup vs baseline: 1.0267x; 1.0008x over previous
//
#include <hip/hip_runtime.h>
#include <hip/hip_bf16.h>

#define IN_DIM 2048
#define OUT_DIM 2048
#define NE 8
#define M_TOT 8192          // B*S = 4*2048
#define NB 4                // batches
#define RK 96               // 8 shared + 64 expert + 24 zero pad

typedef short short8 __attribute__((ext_vector_type(8)));
typedef float floatx4 __attribute__((ext_vector_type(4)));
typedef unsigned short us;

__device__ __forceinline__ us f2bf(float f) {
    __hip_bfloat16 h = __float2bfloat16(f);   // native RNE cast
    return *reinterpret_cast<us*>(&h);
}

__device__ __forceinline__ short8 cvt8(float4 v0, float4 v1) {
    short8 o;
    o[0] = (short)f2bf(v0.x); o[1] = (short)f2bf(v0.y);
    o[2] = (short)f2bf(v0.z); o[3] = (short)f2bf(v0.w);
    o[4] = (short)f2bf(v1.x); o[5] = (short)f2bf(v1.y);
    o[6] = (short)f2bf(v1.z); o[7] = (short)f2bf(v1.w);
    return o;
}

__device__ __forceinline__ void gld_lds16(const void* g, void* l) {
    __builtin_amdgcn_global_load_lds(
        (const __attribute__((address_space(1))) void*)g,
        (__attribute__((address_space(3))) void*)l, 16, 0, 0);
}

// ===========================================================================
// Main GEMM — FROZEN proven kernel (R4 schedule + XCD-chunked mapping:
// 67.1us, FETCH 49MB, 0 conflicts). Do not touch.
// ===========================================================================

template <int KX>
__device__ __forceinline__ void stage2(const us* src, char* lds) {
    gld_lds16(src, lds);
    gld_lds16(src + 128 * KX, lds + 8192);
}

__device__ __forceinline__ void mfma_quad(floatx4 (&acc)[8][4], const short8 (&af)[4],
                                          const short8 (&bf)[4], int mq) {
#pragma unroll
    for (int i = 0; i < 4; ++i)
#pragma unroll
        for (int ni = 0; ni < 4; ++ni)
            acc[mq * 4 + i][ni] =
                __builtin_amdgcn_mfma_f32_16x16x32_bf16(af[i], bf[ni], acc[mq * 4 + i][ni], 0, 0, 0);
}

template <int KX, int SM, int VM0, int VM2, bool RD3>
__device__ __forceinline__ void ktile(
    const us* __restrict__ pA, const us* __restrict__ pB, int k1, int k2,
    const char* smC, const char* smN, char* lwC, char* lwN,
    int ab, int bb,
    short8 (&afA)[4], short8 (&afB)[4], short8 (&bfA)[4], short8 (&bfB)[4],
    floatx4 (&acc)[8][4])
{
    // ---------- p0 ----------
#pragma unroll
    for (int i = 0; i < 4; ++i) afB[i] = *(const short8*)(smC + ab + (4 + i) * 1024);
    asm volatile("s_waitcnt lgkmcnt(4)" ::: "memory");
    __builtin_amdgcn_sched_barrier(0);
    __builtin_amdgcn_s_setprio(1);
    mfma_quad(acc, afA, bfA, 0);
    __builtin_amdgcn_s_setprio(0);
    if (SM & 1) stage2<KX>(pA + k1 + 32, lwN + 32768);
    if (VM0 == 8)      asm volatile("s_waitcnt vmcnt(8)" ::: "memory");
    else if (VM0 == 0) asm volatile("s_waitcnt vmcnt(0)" ::: "memory");
    __builtin_amdgcn_s_barrier();

    // ---------- p1 ----------
#pragma unroll
    for (int i = 0; i < 4; ++i) afA[i] = *(const short8*)(smC + 32768 + ab + (4 + i) * 1024);
#pragma unroll
    for (int i = 0; i < 4; ++i) bfB[i] = *(const short8*)(smC + 32768 + bb + i * 1024);
    asm volatile("s_waitcnt lgkmcnt(8)" ::: "memory");
    __builtin_amdgcn_sched_barrier(0);
    __builtin_amdgcn_s_setprio(1);
    mfma_quad(acc, afB, bfA, 1);
    __builtin_amdgcn_s_setprio(0);
    if (SM & 2) stage2<KX>(pB + k2, lwC + 16384);
    __builtin_amdgcn_s_barrier();

    // ---------- p2 ----------
#pragma unroll
    for (int i = 0; i < 4; ++i) afB[i] = *(const short8*)(smC + 32768 + ab + i * 1024);
    asm volatile("s_waitcnt lgkmcnt(4)" ::: "memory");
    __builtin_amdgcn_sched_barrier(0);
    __builtin_amdgcn_s_setprio(1);
    mfma_quad(acc, afA, bfB, 1);
    __builtin_amdgcn_s_setprio(0);
    if (SM & 4) stage2<KX>(pA + k2, lwC);
    if (VM2 == 8)      asm volatile("s_waitcnt vmcnt(8)" ::: "memory");
    else if (VM2 == 4) asm volatile("s_waitcnt vmcnt(4)" ::: "memory");
    __builtin_amdgcn_s_barrier();

    // ---------- p3 ----------
    if (RD3) {
#pragma unroll
        for (int i = 0; i < 4; ++i) afA[i] = *(const short8*)(smN + ab + i * 1024);
#pragma unroll
        for (int i = 0; i < 4; ++i) bfA[i] = *(const short8*)(smN + bb + i * 1024);
        asm volatile("s_waitcnt lgkmcnt(8)" ::: "memory");
    } else {
        asm volatile("s_waitcnt lgkmcnt(0)" ::: "memory");
    }
    __builtin_amdgcn_sched_barrier(0);
    __builtin_amdgcn_s_setprio(1);
    mfma_quad(acc, afB, bfB, 0);
    __builtin_amdgcn_s_setprio(0);
    if (SM & 8) stage2<KX>(pB + k2 + 32, lwC + 49152);
    __builtin_amdgcn_s_barrier();
}

template <int KX, bool PB>
__global__ __launch_bounds__(512) void main_gemm_t(const us* __restrict__ A,
                                                   const us* __restrict__ Bw,
                                                   const float* __restrict__ bias,
                                                   float* __restrict__ out) {
    extern __shared__ char smem[];
    constexpr int NT = KX / 64;            // 32 or 34 K-tiles
    int tid = threadIdx.x;
    int lane = tid & 63, w = tid >> 6;
    int wm = w >> 2, wn = w & 3;           // 2M x 4N waves; per-wave C = 128x64
    int rlo = lane & 15, kq = lane >> 4;

    // XCD-chunked swizzle (proven): 256 blocks = 8 XCDs x 32 contiguous
    int b = blockIdx.x;
    int bs = (b & 7) * 32 + (b >> 3);
    int m0 = (bs >> 3) * 256, n0 = (bs & 7) * 256;

    const us* B = PB ? (Bw + (size_t)(m0 >> 11) * OUT_DIM * KX) : Bw;

    int swz = (kq ^ ((rlo >> 1) & 3)) * 16;
    int ab = (wm * 128 + rlo) * 64 + swz;            // + mi*1024 + kh*32768
    int bb = 16384 + (wn * 64 + rlo) * 64 + swz;     // + ni*1024 + kh*32768

    // staging source pointers (pre-swizzled global, rule #21)
    int r0 = tid >> 2;
    int ps = tid & 3;
    int ssw = (ps ^ ((r0 >> 1) & 3)) * 8;
    const us* pA = A + (size_t)(m0 + r0) * KX + ssw;
    const us* pB = B + (size_t)(n0 + r0) * KX + ssw;
    char* lw0 = smem + w * 1024;
    char* lw1 = lw0 + 65536;
    const char* sm0 = smem;
    const char* sm1 = smem + 65536;

    floatx4 acc[8][4];
#pragma unroll
    for (int mi = 0; mi < 8; ++mi)
#pragma unroll
        for (int ni = 0; ni < 4; ++ni) acc[mi][ni] = (floatx4)0.f;

    // prologue: 7 halves (tile0 complete; tile1 A.K0,B.K0,B.K1)
    stage2<KX>(pA,      lw0);
    stage2<KX>(pB,      lw0 + 16384);
    stage2<KX>(pA + 32, lw0 + 32768);
    stage2<KX>(pB + 32, lw0 + 49152);
    stage2<KX>(pA + 64, lw1);
    stage2<KX>(pB + 64, lw1 + 16384);
    stage2<KX>(pB + 96, lw1 + 49152);
    asm volatile("s_waitcnt vmcnt(10)" ::: "memory");
    __builtin_amdgcn_s_barrier();

    short8 afA[4], afB[4], bfA[4], bfB[4];
#pragma unroll
    for (int i = 0; i < 4; ++i) afA[i] = *(const short8*)(sm0 + ab + i * 1024);
#pragma unroll
    for (int i = 0; i < 4; ++i) bfA[i] = *(const short8*)(sm0 + bb + i * 1024);

    for (int tt = 0; tt < NT / 2 - 1; ++tt) {
        int t0 = tt * 2;
        ktile<KX, 0xF, 8, 8, true>(pA, pB, (t0 + 1) * 64, (t0 + 2) * 64,
                                   sm0, sm1, lw0, lw1, ab, bb, afA, afB, bfA, bfB, acc);
        ktile<KX, 0xF, 8, 8, true>(pA, pB, (t0 + 2) * 64, (t0 + 3) * 64,
                                   sm1, sm0, lw1, lw0, ab, bb, afA, afB, bfA, bfB, acc);
    }
    ktile<KX, 0x1, 8, 4, true>(pA, pB, (NT - 1) * 64, NT * 64,
                               sm0, sm1, lw0, lw1, ab, bb, afA, afB, bfA, bfB, acc);
    ktile<KX, 0x0, 0, -1, false>(pA, pB, 0, 0,
                                 sm1, sm0, lw1, lw0, ab, bb, afA, afB, bfA, bfB, acc);

    // epilogue: C/D map col=rlo, row=kq*4+reg
    float bbias[4];
#pragma unroll
    for (int ni = 0; ni < 4; ++ni) bbias[ni] = bias[n0 + wn * 64 + ni * 16 + rlo];
#pragma unroll
    for (int mi = 0; mi < 8; ++mi) {
        int row = m0 + wm * 128 + mi * 16 + kq * 4;
#pragma unroll
        for (int ni = 0; ni < 4; ++ni) {
            int col = n0 + wn * 64 + ni * 16 + rlo;
#pragma unroll
            for (int r = 0; r < 4; ++r)
                out[(size_t)(row + r) * OUT_DIM + col] = acc[mi][ni][r] + bbias[ni];
        }
    }
}

// ===========================================================================
// combo (R18): single prep launch, NO tiny_prep dependency.
//  blocks 0..255  : delta GEMM — Bext[b][n][i] = bf16(W + Bcat·diag(rw_b)·Acat^T)
//    · af (scaled Bcat cols) staged PER-ks into static sB[4][256][8] (16KB,
//      2 short8 writes/thread/round, barrier-paired) — fixes R16's 66KB
//      dynamic-LDS occupancy kill + serial 12-slot prologue.
//    · bf (Acat rows) DIRECT from As/Ae (R16-verified: fragment k-range
//      ks*32+kq*8 aligns exactly with one rank-8 block -> one float4x2).
//    · R14/R15-verified LDS-transpose epilogue (coalesced 64B Bext stores).
//  blocks 256..767: x rows -> bf16 panel Aext [8192][2048] (R15 verbatim).
// Static LDS 34.8KB -> 3-4 blocks/CU preserved.
// ===========================================================================
__global__ __launch_bounds__(512) void combo(
    const float* __restrict__ x, const float* __restrict__ W,
    const float* __restrict__ As, const float* __restrict__ Ae,
    const float* __restrict__ Bs, const float* __restrict__ Be,
    const float* __restrict__ rw,
    us* __restrict__ Aext, us* __restrict__ Bext)
{
    __shared__ us sB[4][256][8];     // 16 KB, re-staged each ks
    __shared__ us tr[8][16][72];     // 18.4 KB
    int bid = blockIdx.x;
    int tid = threadIdx.x;

    if (bid >= 256) {
        // ---- x -> bf16 panel, 16 rows/block (R15 verbatim) ----
        int xb = bid - 256;
        int half = tid >> 8;
        int col = (tid & 255) * 8;
#pragma unroll 8
        for (int pass = 0; pass < 8; ++pass) {
            int row = xb * 16 + pass * 2 + half;
            const float4* src = (const float4*)(x + (size_t)row * IN_DIM + col);
            *(short8*)(Aext + (size_t)row * IN_DIM + col) = cvt8(src[0], src[1]);
        }
        return;
    }

    int lane = tid & 63, w = tid >> 6;
    int wm = w >> 2, wn = w & 3;           // wave-tile: 128 (n) x 64 (i)
    int rlo = lane & 15, kq = lane >> 4;
    int b = bid >> 6;
    int t6 = bid & 63;
    int nn0 = (t6 >> 3) * 256, ii0 = (t6 & 7) * 256;

    float er[8];
#pragma unroll
    for (int e = 0; e < 8; ++e) er[e] = rw[b * NE + e];

    floatx4 acc[8][4];
#pragma unroll
    for (int mi = 0; mi < 8; ++mi)
#pragma unroll
        for (int ni = 0; ni < 4; ++ni) acc[mi][ni] = (floatx4)0.f;

#pragma unroll
    for (int ks = 0; ks < 3; ++ks) {
        __syncthreads();   // protect previous round's sB reads
        // stage 4 slots (k = ks*32 .. ks*32+31) of scaled Bcat: 2 writes/thread
#pragma unroll
        for (int q = 0; q < 2; ++q) {
            int idx = q * 512 + tid;
            int r = idx & 255, jl = idx >> 8;
            int n = nn0 + r;
            int kbase = (ks * 4 + jl) * 8;
            short8 v;
#pragma unroll
            for (int kk = 0; kk < 8; ++kk) {
                int k = kbase + kk;
                float val = 0.f;
                if (k < 8)       val = Bs[(size_t)k * OUT_DIM + n];
                else if (k < 72) val = Be[(size_t)(k - 8) * OUT_DIM + n] * er[(k - 8) >> 3];
                v[kk] = (short)f2bf(val);
            }
            *(short8*)&sB[jl][r][0] = v;
        }
        __syncthreads();

        short8 af[8], bf[4];
#pragma unroll
        for (int mi = 0; mi < 8; ++mi)
            af[mi] = *(const short8*)&sB[kq][wm * 128 + mi * 16 + rlo][0];
#pragma unroll
        for (int ni = 0; ni < 4; ++ni) {
            int i = ii0 + wn * 64 + ni * 16 + rlo;
            short8 bfv = (short8)0;
            if (ks == 0) {
                const float* src = (kq == 0) ? As + (size_t)i * 8
                                             : Ae + ((size_t)(kq - 1) * IN_DIM + i) * 8;
                bfv = cvt8(((const float4*)src)[0], ((const float4*)src)[1]);
            } else if (ks == 1) {
                const float* src = Ae + ((size_t)(kq + 3) * IN_DIM + i) * 8;
                bfv = cvt8(((const float4*)src)[0], ((const float4*)src)[1]);
            } else {
                if (kq == 0) {
                    const float* src = Ae + ((size_t)7 * IN_DIM + i) * 8;
                    bfv = cvt8(((const float4*)src)[0], ((const float4*)src)[1]);
                }
            }
            bf[ni] = bfv;
        }
#pragma unroll
        for (int mi = 0; mi < 8; ++mi)
#pragma unroll
            for (int ni = 0; ni < 4; ++ni)
                acc[mi][ni] = __builtin_amdgcn_mfma_f32_16x16x32_bf16(
                    af[mi], bf[ni], acc[mi][ni], 0, 0, 0);
    }

    // epilogue via LDS transpose (R14/R15 verified); wave-local
    int icol = ii0 + wn * 64;
    int rr = lane >> 2, sl = lane & 3;
#pragma unroll
    for (int mi = 0; mi < 8; ++mi) {
        int n_base = nn0 + wm * 128 + mi * 16;
#pragma unroll
        for (int ni = 0; ni < 4; ++ni)
#pragma unroll
            for (int r = 0; r < 4; ++r) {
                int row = kq * 4 + r;
                float val = acc[mi][ni][r]
                          + W[(size_t)(n_base + row) * IN_DIM + icol + ni * 16 + rlo];
                tr[w][row][ni * 16 + rlo] = f2bf(val);
            }
        asm volatile("s_waitcnt lgkmcnt(0)" ::: "memory");
#pragma unroll
        for (int p = 0; p < 2; ++p) {
            int c0 = (sl + p * 4) * 8;
            short8 v = *(const short8*)&tr[w][rr][c0];
            *(short8*)&Bext[((size_t)b * OUT_DIM + n_base + rr) * IN_DIM + icol + c0] = v;
        }
        asm volatile("s_waitcnt lgkmcnt(0)" ::: "memory");
    }
}

// ===========================================================================
// FALLBACK PATH (exact R6, proven) — used only if ws too small.
// ===========================================================================
#define K_EXT1 2176
#define RANK_PAD 128

__global__ void prep_wb_fb(const float* __restrict__ W, const float* __restrict__ Bs,
                           const float* __restrict__ Be, const float* __restrict__ As,
                           const float* __restrict__ Ae, us* __restrict__ Bext,
                           us* __restrict__ AcatT) {
    int blk = blockIdx.x;
    int t = threadIdx.x;
    if (blk < OUT_DIM) {
        int n = blk;
        const float4* src = (const float4*)(W + (size_t)n * IN_DIM + t * 8);
        *(short8*)(Bext + (size_t)n * K_EXT1 + t * 8) = cvt8(src[0], src[1]);
        if (t < RANK_PAD) {
            float v = 0.f;
            if (t < 8)       v = Bs[(size_t)t * OUT_DIM + n];
            else if (t < 72) v = Be[(size_t)(t - 8) * OUT_DIM + n];
            Bext[(size_t)n * K_EXT1 + IN_DIM + t] = f2bf(v);
        }
    } else {
        int kp = blk - OUT_DIM;
        int i0 = t * 8;
        short8 o;
#pragma unroll
        for (int j = 0; j < 8; ++j) {
            int i = i0 + j;
            float v = 0.f;
            if (kp < 8)       v = As[(size_t)i * 8 + kp];
            else if (kp < 72) v = Ae[(size_t)((kp - 8) >> 3) * IN_DIM * 8 + (size_t)i * 8 + ((kp - 8) & 7)];
            o[j] = (short)f2bf(v);
        }
        *(short8*)(AcatT + (size_t)kp * IN_DIM + i0) = o;
    }
}

__global__ __launch_bounds__(512) void tgemm_fused_fb(const float* __restrict__ x,
                                                      us* __restrict__ Aext,
                                                      const us* __restrict__ AcatT,
                                                      const float* __restrict__ routing) {
    __shared__ floatx4 red[8][64][6];
    int tid = threadIdx.x;
    int lane = tid & 63, w = tid >> 6;
    int rlo = lane & 15, kq = lane >> 4;
    int mbase = blockIdx.x * 16;

    floatx4 acc[6];
#pragma unroll
    for (int ni = 0; ni < 6; ++ni) acc[ni] = (floatx4)0.f;

    const float* xrow = x + (size_t)(mbase + rlo) * IN_DIM + w * 256 + kq * 8;
    us* arow = Aext + (size_t)(mbase + rlo) * K_EXT1 + w * 256 + kq * 8;
    const us* bbase = AcatT + (size_t)rlo * IN_DIM + w * 256 + kq * 8;

#pragma unroll
    for (int kt = 0; kt < 8; ++kt) {
        int k0 = kt * 32;
        float4 v0 = *(const float4*)(xrow + k0);
        float4 v1 = *(const float4*)(xrow + k0 + 4);
        short8 a = cvt8(v0, v1);
        *(short8*)(arow + k0) = a;
#pragma unroll
        for (int ni = 0; ni < 6; ++ni) {
            short8 bfr = *(const short8*)(bbase + (size_t)(ni * 16) * IN_DIM + k0);
            acc[ni] = __builtin_amdgcn_mfma_f32_16x16x32_bf16(a, bfr, acc[ni], 0, 0, 0);
        }
    }

#pragma unroll
    for (int ni = 0; ni < 6; ++ni) red[w][lane][ni] = acc[ni];
    __syncthreads();
    if (w == 0) {
#pragma unroll
        for (int ni = 0; ni < 6; ++ni) {
            floatx4 s = red[0][lane][ni];
#pragma unroll
            for (int ww = 1; ww < 8; ++ww) s += red[ww][lane][ni];
            int col = ni * 16 + rlo;
#pragma unroll
            for (int r = 0; r < 4; ++r) {
                int row = mbase + kq * 4 + r;
                float fac = (col < 8) ? 1.f
                          : (col < 72 ? routing[(row >> 11) * NE + ((col - 8) >> 3)] : 0.f);
                Aext[(size_t)row * K_EXT1 + IN_DIM + col] = f2bf(s[r] * fac);
            }
        }
#pragma unroll
        for (int c = 0; c < 2; ++c) {
            int col = 96 + c * 16 + rlo;
#pragma unroll
            for (int r = 0; r < 4; ++r)
                Aext[(size_t)(mbase + kq * 4 + r) * K_EXT1 + IN_DIM + col] = 0;
        }
    }
}

// ===========================================================================
extern "C" void kernel_launch(void* const* d_in, const int* in_sizes, int n_in,
                              void* d_out, int out_size, void* d_ws, size_t ws_size,
                              hipStream_t stream) {
    const float* x   = (const float*)d_in[0];
    const float* rw  = (const float*)d_in[1];
    const float* W   = (const float*)d_in[2];
    const float* bv  = (const float*)d_in[3];
    const float* As  = (const float*)d_in[4];
    const float* Bs  = (const float*)d_in[5];
    const float* Ae  = (const float*)d_in[6];
    const float* Be  = (const float*)d_in[7];
    float* out = (float*)d_out;

    // primary layout
    size_t pA  = 0;                                               // Aext  [8192][2048] bf16
    size_t pB  = pA + (size_t)M_TOT * IN_DIM * 2;                 // Bext  [4][2048][2048] bf16
    size_t need2 = pB + (size_t)NB * OUT_DIM * IN_DIM * 2;        // ~67.1 MB

    if (ws_size >= need2) {
        us* Aext = (us*)((char*)d_ws + pA);
        us* Bext = (us*)((char*)d_ws + pB);

        hipFuncSetAttribute((const void*)&main_gemm_t<2048, true>,
                            hipFuncAttributeMaxDynamicSharedMemorySize, 131072);

        combo<<<768, 512, 0, stream>>>(x, W, As, Ae, Bs, Be, rw, Aext, Bext);
        main_gemm_t<2048, true><<<256, 512, 131072, stream>>>(Aext, Bext, bv, out);
        return;
    }

    // fallback: proven R6 path (K=2176 concat)
    size_t fA = 0;
    size_t fB = fA + (size_t)M_TOT * K_EXT1 * 2;
    size_t fC = fB + (size_t)OUT_DIM * K_EXT1 * 2;
    size_t need1 = fC + (size_t)96 * IN_DIM * 2;
    if (ws_size < need1) return;

    us* Aext  = (us*)((char*)d_ws + fA);
    us* Bext  = (us*)((char*)d_ws + fB);
    us* AcatT = (us*)((char*)d_ws + fC);

    hipFuncSetAttribute((const void*)&main_gemm_t<2176, false>,
                        hipFuncAttributeMaxDynamicSharedMemorySize, 131072);

    prep_wb_fb<<<OUT_DIM + 96, 256, 0, stream>>>(W, Bs, Be, As, Ae, Bext, AcatT);
    tgemm_fused_fb<<<M_TOT / 16, 512, 0, stream>>>(x, Aext, AcatT, rw);
    main_gemm_t<2176, false><<<256, 512, 131072, stream>>>(Aext, Bext, bv, out);
}